// Round 8
// baseline (1196.187 us; speedup 1.0000x reference)
//
#include <hip/hip_runtime.h>
#include <hip/hip_cooperative_groups.h>
#include <math.h>

namespace cg = cooperative_groups;

#define N_USERS 40000
#define N_ITEMS 20000
#define NNODES  60000          // N_USERS + N_ITEMS
#define D       128
#define N_EDGES 320000
#define NDIR    (2 * N_EDGES)  // directed edges
#define EPS_    1e-7f
#define BATCH   4096
#define GRID    1024           // 4 blocks/CU x 256 CUs, guaranteed by launch_bounds

__device__ __forceinline__ unsigned bf16x2_pack(float a, float b) {
    unsigned ua = __float_as_uint(a);
    unsigned ub = __float_as_uint(b);
    ua = (ua + 0x7FFF + ((ua >> 16) & 1)) >> 16;
    ub = (ub + 0x7FFF + ((ub >> 16) & 1)) >> 16;
    return ua | (ub << 16);
}
__device__ __forceinline__ float bf16_lo(unsigned p) { return __uint_as_float(p << 16); }
__device__ __forceinline__ float bf16_hi(unsigned p) { return __uint_as_float(p & 0xFFFF0000u); }

__device__ __forceinline__ void add_u4(float* acc, uint4 t) {
    acc[0] += bf16_lo(t.x); acc[1] += bf16_hi(t.x);
    acc[2] += bf16_lo(t.y); acc[3] += bf16_hi(t.y);
    acc[4] += bf16_lo(t.z); acc[5] += bf16_hi(t.z);
    acc[6] += bf16_lo(t.w); acc[7] += bf16_hi(t.w);
}

// full-wave row gather: 4 quarters take edges j = s+q, s+q+4, ...; butterfly at end.
// After return every lane holds the row-total for its sub (lane&15) in a[0..8).
__device__ __forceinline__ void gather_row_wave(int row, int q, int sub,
                                                const int* base, const int* col,
                                                const uint4* z, float* a) {
    int s = base[row], e = base[row + 1];
    #pragma unroll
    for (int k = 0; k < 8; ++k) a[k] = 0.0f;
    for (int j = s + q; j < e; j += 4) {
        uint4 t = z[(col[j] << 4) + sub];
        add_u4(a, t);
    }
    #pragma unroll
    for (int k = 0; k < 8; ++k) {
        a[k] += __shfl_xor(a[k], 16);
        a[k] += __shfl_xor(a[k], 32);
    }
}

__global__ __launch_bounds__(256, 4) void mega(
        const float4* __restrict__ ue, const float4* __restrict__ ie,
        const int* __restrict__ au, const int* __restrict__ ai,
        const int* __restrict__ usr, const int* __restrict__ pos,
        const int* __restrict__ neg, float* __restrict__ out, void* wsv) {
    cg::grid_group grid = cg::this_grid();

    // ws layout (16B-aligned): z0|z1|z2 (bf16) | dinv | dinv2 |
    // [cnt | fillc | lacc |pad] | base[60008] | col[NDIR] | bsum[GRID]
    const size_t XNH = (size_t)NNODES * D / 2;
    unsigned* z0    = (unsigned*)wsv;
    unsigned* z1    = z0 + XNH;
    unsigned* z2    = z1 + XNH;
    float*    dinv  = (float*)(z2 + XNH);
    float*    dinv2 = dinv + NNODES;
    int*      cnt   = (int*)(dinv2 + NNODES);
    int*      fillc = cnt + NNODES;
    float*    lacc  = (float*)(fillc + NNODES);
    int*      base  = (int*)(lacc + 4);
    int*      col   = base + 60008;
    int*      bsum  = col + NDIR;

    const int tid   = threadIdx.x;
    const int gtid  = blockIdx.x * 256 + tid;
    const int nthr  = gridDim.x * 256;
    const int lane  = tid & 63;
    const int wv    = tid >> 6;
    const int q     = lane >> 4;
    const int sub   = lane & 15;

    __shared__ int   sred[4];
    __shared__ int   stile[256];
    __shared__ int   sbcast;
    __shared__ float rowbuf[3][128];

    // ---- P0: zero cnt, fillc, lacc (+pad) --------------------------------
    for (int i = gtid; i < 2 * NNODES + 4; i += nthr) cnt[i] = 0;
    grid.sync();

    // ---- P1: degree count ------------------------------------------------
    for (int e = gtid; e < N_EDGES; e += nthr) {
        atomicAdd(&cnt[au[e]], 1);
        atomicAdd(&cnt[N_USERS + ai[e]], 1);
    }
    grid.sync();

    // ---- P2a: dinv/dinv2 + per-block chunk sums --------------------------
    const int chunk = (NNODES + gridDim.x - 1) / gridDim.x;
    const int lo = blockIdx.x * chunk;
    const int hi = min(lo + chunk, NNODES);
    {
        int part = 0;
        for (int i = lo + tid; i < hi; i += 256) {
            int v = cnt[i];
            float w = rsqrtf((float)v + EPS_);
            dinv[i] = w; dinv2[i] = w * w;
            part += v;
        }
        #pragma unroll
        for (int off = 32; off; off >>= 1) part += __shfl_down(part, off);
        if (lane == 0) sred[wv] = part;
        __syncthreads();
        if (tid == 0) bsum[blockIdx.x] = sred[0] + sred[1] + sred[2] + sred[3];
    }
    grid.sync();

    // ---- P2b: exclusive block offset + chunk scan -> base ----------------
    {
        int pre = 0;
        for (int t = tid; t < blockIdx.x; t += 256) pre += bsum[t];
        #pragma unroll
        for (int off = 32; off; off >>= 1) pre += __shfl_down(pre, off);
        if (lane == 0) sred[wv] = pre;
        __syncthreads();
        if (tid == 0) sbcast = sred[0] + sred[1] + sred[2] + sred[3];
        __syncthreads();
        int run = sbcast;
        for (int t0 = lo; t0 < hi; t0 += 256) {
            int i = t0 + tid;
            int v = (i < hi) ? cnt[i] : 0;
            stile[tid] = v;
            __syncthreads();
            for (int off = 1; off < 256; off <<= 1) {
                int u2 = (tid >= off) ? stile[tid - off] : 0;
                __syncthreads();
                stile[tid] += u2;
                __syncthreads();
            }
            if (i < hi) base[i] = run + stile[tid] - v;
            run += stile[255];
            __syncthreads();
        }
        if (gtid == 0) base[NNODES] = NDIR;
    }
    grid.sync();

    // ---- P3: CSR fill + z0 init ------------------------------------------
    for (int e = gtid; e < NDIR; e += nthr) {
        int r, c;
        if (e < N_EDGES) { r = au[e];                  c = N_USERS + ai[e]; }
        else             { int k = e - N_EDGES; r = N_USERS + ai[k]; c = au[k]; }
        int p2 = base[r] + atomicAdd(&fillc[r], 1);
        col[p2] = c;
    }
    {
        const int NU4 = N_USERS * D / 4, NT4 = NNODES * D / 4;
        for (int i = gtid; i < NT4; i += nthr) {
            float4 v = (i < NU4) ? ue[i] : ie[i - NU4];
            float w = dinv[i >> 5];
            uint2 p2;
            p2.x = bf16x2_pack(v.x * w, v.y * w);
            p2.y = bf16x2_pack(v.z * w, v.w * w);
            ((uint2*)z0)[i] = p2;
        }
    }
    grid.sync();

    // ---- P4/P5: two SpMM layers, full-wave per row -----------------------
    const int wave   = gtid >> 6;
    const int nwaves = nthr >> 6;
    {
        const uint4* zin  = (const uint4*)z0;
        uint4*       zout = (uint4*)z1;
        for (int row = wave; row < NNODES; row += nwaves) {
            float a[8];
            gather_row_wave(row, q, sub, base, col, zin, a);
            if (q == 0) {
                float w = dinv2[row];
                uint4 o;
                o.x = bf16x2_pack(w * a[0], w * a[1]);
                o.y = bf16x2_pack(w * a[2], w * a[3]);
                o.z = bf16x2_pack(w * a[4], w * a[5]);
                o.w = bf16x2_pack(w * a[6], w * a[7]);
                zout[(row << 4) + sub] = o;
            }
        }
    }
    grid.sync();
    {
        const uint4* zin  = (const uint4*)z1;
        uint4*       zout = (uint4*)z2;
        for (int row = wave; row < NNODES; row += nwaves) {
            float a[8];
            gather_row_wave(row, q, sub, base, col, zin, a);
            if (q == 0) {
                float w = dinv2[row];
                uint4 o;
                o.x = bf16x2_pack(w * a[0], w * a[1]);
                o.y = bf16x2_pack(w * a[2], w * a[3]);
                o.z = bf16x2_pack(w * a[4], w * a[5]);
                o.w = bf16x2_pack(w * a[6], w * a[7]);
                zout[(row << 4) + sub] = o;
            }
        }
    }
    grid.sync();

    // ---- P6: BPR loss. Block handles elements grid-strided; waves 0-2
    // gather zsum rows of u/p/n into LDS (layer-3 inline, f32); wave 0 dots.
    {
        float lreg = 0.0f;   // meaningful on (wv==0, lane==0)
        for (int el = blockIdx.x; el < BATCH; el += gridDim.x) {
            int u = usr[el];
            int p = N_USERS + pos[el] - 1;   // 1-indexed items
            int n = N_USERS + neg[el] - 1;
            if (wv < 3) {
                int node = (wv == 0) ? u : (wv == 1) ? p : n;
                float a[8];
                gather_row_wave(node, q, sub, base, col, (const uint4*)z2, a);
                if (q == 0) {
                    float w = dinv2[node];
                    int o = (node << 4) + sub;
                    float v[8] = {0, 0, 0, 0, 0, 0, 0, 0};
                    add_u4(v, ((const uint4*)z0)[o]);
                    add_u4(v, ((const uint4*)z1)[o]);
                    add_u4(v, ((const uint4*)z2)[o]);
                    #pragma unroll
                    for (int k = 0; k < 8; ++k)
                        rowbuf[wv][sub * 8 + k] = v[k] + w * a[k];
                }
            }
            __syncthreads();
            if (wv == 0) {
                float u0 = rowbuf[0][2 * lane], u1 = rowbuf[0][2 * lane + 1];
                float sp = u0 * rowbuf[1][2 * lane] + u1 * rowbuf[1][2 * lane + 1];
                float sn = u0 * rowbuf[2][2 * lane] + u1 * rowbuf[2][2 * lane + 1];
                #pragma unroll
                for (int off = 32; off; off >>= 1) {
                    sp += __shfl_down(sp, off);
                    sn += __shfl_down(sn, off);
                }
                if (lane == 0) {
                    float du = dinv[u], dp = dinv[p], dn = dinv[n];
                    float diff = (sp / (du * dp) - sn / (du * dn)) * (1.0f / 16.0f);
                    lreg += fminf(diff, 0.0f) - log1pf(expf(-fabsf(diff)));
                }
            }
            __syncthreads();
        }
        if (wv == 0 && lane == 0) atomicAdd(lacc, lreg);
    }
    grid.sync();

    if (gtid == 0) out[0] = -atomicAdd(lacc, 0.0f) * (1.0f / (float)BATCH);
}

extern "C" void kernel_launch(void* const* d_in, const int* in_sizes, int n_in,
                              void* d_out, int out_size, void* d_ws, size_t ws_size,
                              hipStream_t stream) {
    const float4* ue  = (const float4*)d_in[0];
    const float4* ie  = (const float4*)d_in[1];
    const int*    au  = (const int*)d_in[2];
    const int*    ai  = (const int*)d_in[3];
    const int*    usr = (const int*)d_in[4];
    const int*    pos = (const int*)d_in[5];
    const int*    neg = (const int*)d_in[6];
    float*        out = (float*)d_out;
    void*         ws  = d_ws;

    void* args[] = { (void*)&ue, (void*)&ie, (void*)&au, (void*)&ai,
                     (void*)&usr, (void*)&pos, (void*)&neg, (void*)&out,
                     (void*)&ws };
    hipLaunchCooperativeKernel((const void*)mega, dim3(GRID), dim3(256),
                               args, 0, stream);
}

// Round 10
// 225.564 us; speedup vs baseline: 5.3031x; 5.3031x over previous
//
#include <hip/hip_runtime.h>
#include <math.h>

#define N_USERS 40000
#define N_ITEMS 20000
#define NNODES  60000          // N_USERS + N_ITEMS
#define D       128
#define N_EDGES 320000
#define NDIR    (2 * N_EDGES)  // directed edges
#define EPS_    1e-7f
#define BATCH   4096
#define STRIDE  64             // ELL row capacity (max degree ~44 for Poisson(16))
#define ZSCALE  256.0f         // fp8 storage scale; folded out in bpr
#define NBLK    ((NNODES + 255) / 256)     // 235
#define BPR_BLOCKS (BATCH / 4)             // 1024, one wave per element
#define FILL_BLOCKS (NDIR / 256)           // 2500
#define INIT_BLOCKS (NNODES * D / 8 / 256) // 3750 (8 elems per thread)

typedef float vf2 __attribute__((ext_vector_type(2)));

// unpack 8 fp8 (e4m3) from uint2, add into acc[0..8)
__device__ __forceinline__ void add_fp8x8(float* a, uint2 t) {
    vf2 p0 = __builtin_amdgcn_cvt_pk_f32_fp8(t.x, false);
    vf2 p1 = __builtin_amdgcn_cvt_pk_f32_fp8(t.x, true);
    vf2 p2 = __builtin_amdgcn_cvt_pk_f32_fp8(t.y, false);
    vf2 p3 = __builtin_amdgcn_cvt_pk_f32_fp8(t.y, true);
    a[0] += p0.x; a[1] += p0.y; a[2] += p1.x; a[3] += p1.y;
    a[4] += p2.x; a[5] += p2.y; a[6] += p3.x; a[7] += p3.y;
}

// pack 8 f32 -> 8 fp8 (e4m3) into uint2, clamped to the e4m3 range (+-448)
// so no stored byte can be NaN even for pathological (zero-degree) rows.
__device__ __forceinline__ uint2 pack_fp8x8(const float* vin) {
    float v[8];
    #pragma unroll
    for (int k = 0; k < 8; ++k) v[k] = fminf(fmaxf(vin[k], -448.0f), 448.0f);
    int lo = __builtin_amdgcn_cvt_pk_fp8_f32(v[0], v[1], 0,  false);
    lo     = __builtin_amdgcn_cvt_pk_fp8_f32(v[2], v[3], lo, true);
    int hi = __builtin_amdgcn_cvt_pk_fp8_f32(v[4], v[5], 0,  false);
    hi     = __builtin_amdgcn_cvt_pk_fp8_f32(v[6], v[7], hi, true);
    return make_uint2((unsigned)lo, (unsigned)hi);
}

// ---- degree count (int): cnt[r] += 1 per directed edge -------------------
__global__ void deg_count(const int* __restrict__ au, const int* __restrict__ ai,
                          int* __restrict__ cnt) {
    int e = blockIdx.x * blockDim.x + threadIdx.x;
    if (e >= N_EDGES) return;
    atomicAdd(&cnt[au[e]], 1);
    atomicAdd(&cnt[N_USERS + ai[e]], 1);
}

// ---- dinv[i] = (cnt[i]+eps)^-1/2 ; dinv2 = dinv^2 ------------------------
__global__ void make_dinv(const int* __restrict__ cnt, float* __restrict__ dinv,
                          float* __restrict__ dinv2) {
    int i = blockIdx.x * blockDim.x + threadIdx.x;
    if (i >= NNODES) return;
    float w = rsqrtf((float)cnt[i] + EPS_);
    dinv[i] = w;
    dinv2[i] = w * w;
}

// ---- fused ELL fill + z0 init (disjoint block ranges) --------------------
__global__ void fill_and_init(const int* __restrict__ au, const int* __restrict__ ai,
                              int* __restrict__ fillc, int* __restrict__ colell,
                              const float4* __restrict__ ue, const float4* __restrict__ ie,
                              const float* __restrict__ dinv, uint2* __restrict__ z0) {
    if (blockIdx.x < FILL_BLOCKS) {
        int e = blockIdx.x * 256 + threadIdx.x;
        int r, c;
        if (e < N_EDGES) { r = au[e];                  c = N_USERS + ai[e]; }
        else             { int k = e - N_EDGES; r = N_USERS + ai[k]; c = au[k]; }
        int pos = atomicAdd(&fillc[r], 1);
        if (pos < STRIDE) colell[(r << 6) + pos] = c;
    } else {
        // 8 elems per thread: two float4 loads -> one uint2 (8 fp8)
        const int NU4 = N_USERS * D / 4;
        int i = (blockIdx.x - FILL_BLOCKS) * 256 + threadIdx.x;  // < NNODES*D/8
        int f4 = i * 2;
        float4 v0, v1;
        if (f4 < NU4) { v0 = ue[f4];       v1 = ue[f4 + 1]; }
        else          { v0 = ie[f4 - NU4]; v1 = ie[f4 + 1 - NU4]; }
        float w = dinv[i >> 4] * ZSCALE;   // 16 threads per row of 128
        float v[8] = { v0.x * w, v0.y * w, v0.z * w, v0.w * w,
                       v1.x * w, v1.y * w, v1.z * w, v1.w * w };
        z0[i] = pack_fp8x8(v);
    }
}

// ---- SpMM, quarter-wave rows: 16 lanes x uint2 = 128B fp8 row ------------
// znxt[r] = fp8( dinv2[r] * sum_{c in N(r)} z[c] )   (scale preserved)
__global__ void spmm_full(const int* __restrict__ cnt, const int* __restrict__ colell,
                          const float* __restrict__ dinv2,
                          const uint2* __restrict__ z, uint2* __restrict__ znxt) {
    int tid = blockIdx.x * 256 + threadIdx.x;
    int row = tid >> 4;               // 16 rows per 256-thread block
    int sub = threadIdx.x & 15;
    if (row >= NNODES) return;
    int e = cnt[row];
    const int* rc = colell + (row << 6);
    float a0[8] = {0,0,0,0,0,0,0,0};
    float a1[8] = {0,0,0,0,0,0,0,0};
    int j = 0;
    for (; j + 3 < e; j += 4) {
        int c0 = rc[j], c1 = rc[j + 1], c2 = rc[j + 2], c3 = rc[j + 3];
        uint2 t0 = z[(c0 << 4) + sub];   // row stride = 16 uint2
        uint2 t1 = z[(c1 << 4) + sub];
        uint2 t2 = z[(c2 << 4) + sub];
        uint2 t3 = z[(c3 << 4) + sub];
        add_fp8x8(a0, t0); add_fp8x8(a1, t1);
        add_fp8x8(a0, t2); add_fp8x8(a1, t3);
    }
    for (; j < e; ++j) {
        uint2 t0 = z[(rc[j] << 4) + sub];
        add_fp8x8(a0, t0);
    }
    float w = dinv2[row];
    float v[8];
    #pragma unroll
    for (int k = 0; k < 8; ++k) v[k] = w * (a0[k] + a1[k]);
    znxt[(row << 4) + sub] = pack_fp8x8(v);
}

// ---- fused BPR loss, quarter-wave: one wave per element, u/p/n in q0/q1/q2
// zsum[node] = dinv*ZSCALE*emb (f32, exact) + z1 + z2 + inline layer-3 from z2.
// diff = (sp/(du*dp) - sn/(du*dn)) / (16 * ZSCALE^2)
__global__ void bpr_loss(const float4* __restrict__ ue, const float4* __restrict__ ie,
                         const uint2* __restrict__ z1, const uint2* __restrict__ z2,
                         const float* __restrict__ dinv, const float* __restrict__ dinv2,
                         const int* __restrict__ cnt, const int* __restrict__ colell,
                         const int* __restrict__ user, const int* __restrict__ pos,
                         const int* __restrict__ neg,
                         float* __restrict__ lacc, int* __restrict__ done,
                         float* __restrict__ out) {
    __shared__ float s[4];
    int gw   = (blockIdx.x * 256 + threadIdx.x) >> 6;   // batch element
    int lane = threadIdx.x & 63;
    int sub  = lane & 15;
    int q    = lane >> 4;
    int u = user[gw];
    int p = N_USERS + pos[gw] - 1;   // 1-indexed items
    int n = N_USERS + neg[gw] - 1;
    int node = (q == 1) ? p : (q == 2) ? n : u;
    float vals[8] = {0,0,0,0,0,0,0,0};
    if (q < 3) {
        // layer-0 contribution exact from the f32 embeddings
        float4 e0, e1;
        if (node < N_USERS) {
            int b4 = node * 32 + sub * 2;           // 32 float4 per row
            e0 = ue[b4]; e1 = ue[b4 + 1];
        } else {
            int b4 = (node - N_USERS) * 32 + sub * 2;
            e0 = ie[b4]; e1 = ie[b4 + 1];
        }
        float w0 = dinv[node] * ZSCALE;
        vals[0] = w0 * e0.x; vals[1] = w0 * e0.y;
        vals[2] = w0 * e0.z; vals[3] = w0 * e0.w;
        vals[4] = w0 * e1.x; vals[5] = w0 * e1.y;
        vals[6] = w0 * e1.z; vals[7] = w0 * e1.w;
        int o = (node << 4) + sub;
        add_fp8x8(vals, z1[o]);
        add_fp8x8(vals, z2[o]);
        // inline layer-3 gather (f32, no extra rounding)
        int e = cnt[node];
        const int* rc = colell + (node << 6);
        float a0[8] = {0,0,0,0,0,0,0,0};
        float a1[8] = {0,0,0,0,0,0,0,0};
        int j = 0;
        for (; j + 3 < e; j += 4) {
            int c0 = rc[j], c1 = rc[j + 1], c2 = rc[j + 2], c3 = rc[j + 3];
            uint2 t0 = z2[(c0 << 4) + sub];
            uint2 t1 = z2[(c1 << 4) + sub];
            uint2 t2 = z2[(c2 << 4) + sub];
            uint2 t3 = z2[(c3 << 4) + sub];
            add_fp8x8(a0, t0); add_fp8x8(a1, t1);
            add_fp8x8(a0, t2); add_fp8x8(a1, t3);
        }
        for (; j < e; ++j) {
            uint2 t0 = z2[(rc[j] << 4) + sub];
            add_fp8x8(a0, t0);
        }
        float w = dinv2[node];
        #pragma unroll
        for (int k = 0; k < 8; ++k) vals[k] += w * (a0[k] + a1[k]);
    }
    // pull quarter-0 (u-row) values into every quarter: srcLane = sub
    float dotp = 0.0f;
    #pragma unroll
    for (int k = 0; k < 8; ++k) {
        float av = __shfl(vals[k], sub);
        dotp += av * vals[k];
    }
    #pragma unroll
    for (int off = 8; off; off >>= 1) dotp += __shfl_down(dotp, off, 16);
    float sp = __shfl(dotp, 16);   // quarter 1 sub 0 holds u.p
    float sn = __shfl(dotp, 32);   // quarter 2 sub 0 holds u.n
    if (lane == 0) {
        float du = dinv[u], dp = dinv[p], dn = dinv[n];
        const float inv = 1.0f / (16.0f * ZSCALE * ZSCALE);
        float diff = (sp / (du * dp) - sn / (du * dn)) * inv;
        // log_sigmoid(x) = min(x,0) - log1p(exp(-|x|))
        s[threadIdx.x >> 6] = fminf(diff, 0.0f) - log1pf(expf(-fabsf(diff)));
    }
    __syncthreads();
    if (threadIdx.x == 0) {
        atomicAdd(lacc, s[0] + s[1] + s[2] + s[3]);
        __threadfence();
        int prev = atomicAdd(done, 1);
        if (prev == BPR_BLOCKS - 1) {
            float total = atomicAdd(lacc, 0.0f);   // coherent read
            out[0] = -total * (1.0f / (float)BATCH);
        }
    }
}

extern "C" void kernel_launch(void* const* d_in, const int* in_sizes, int n_in,
                              void* d_out, int out_size, void* d_ws, size_t ws_size,
                              hipStream_t stream) {
    const float* ue  = (const float*)d_in[0];
    const float* ie  = (const float*)d_in[1];
    const int*   au  = (const int*)d_in[2];
    const int*   ai  = (const int*)d_in[3];
    const int*   usr = (const int*)d_in[4];
    const int*   pos = (const int*)d_in[5];
    const int*   neg = (const int*)d_in[6];
    float*       out = (float*)d_out;

    const size_t ZNQ = (size_t)NNODES * 16;   // uint2 per fp8 z buffer (128 B/row)

    // ws layout (16B-aligned chunks):
    // z0 | z1 | z2 (fp8) | dinv | dinv2 | [cnt | fillc | lacc | done] | colell
    uint2* z0    = (uint2*)d_ws;
    uint2* z1    = z0 + ZNQ;
    uint2* z2    = z1 + ZNQ;
    float* dinv  = (float*)(z2 + ZNQ);
    float* dinv2 = dinv + NNODES;
    int*   cnt   = (int*)(dinv2 + NNODES);
    int*   fillc = cnt + NNODES;
    float* lacc  = (float*)(fillc + NNODES);
    int*   done  = (int*)(lacc + 1);
    int*   colell = (int*)(lacc + 4);         // NNODES * STRIDE ints

    // cnt + fillc + lacc + done zeroed in one shot
    hipMemsetAsync(cnt, 0, (2 * NNODES + 4) * sizeof(int), stream);

    deg_count<<<(N_EDGES + 255) / 256, 256, 0, stream>>>(au, ai, cnt);
    make_dinv<<<NBLK, 256, 0, stream>>>(cnt, dinv, dinv2);
    fill_and_init<<<FILL_BLOCKS + INIT_BLOCKS, 256, 0, stream>>>(
        au, ai, fillc, colell, (const float4*)ue, (const float4*)ie, dinv, z0);

    const int FULL_BLOCKS = (NNODES + 15) / 16;   // 16 rows per block
    spmm_full<<<FULL_BLOCKS, 256, 0, stream>>>(cnt, colell, dinv2, z0, z1);
    spmm_full<<<FULL_BLOCKS, 256, 0, stream>>>(cnt, colell, dinv2, z1, z2);

    bpr_loss<<<BPR_BLOCKS, 256, 0, stream>>>((const float4*)ue, (const float4*)ie,
                                             z1, z2, dinv, dinv2, cnt, colell,
                                             usr, pos, neg, lacc, done, out);
}

// Round 11
// 185.907 us; speedup vs baseline: 6.4343x; 1.2133x over previous
//
#include <hip/hip_runtime.h>
#include <math.h>

#define N_USERS 40000
#define N_ITEMS 20000
#define NNODES  60000          // N_USERS + N_ITEMS
#define D       128
#define N_EDGES 320000
#define NDIR    (2 * N_EDGES)  // directed edges
#define EPS_    1e-7f
#define BATCH   4096
#define STRIDE  64             // ELL row capacity (max degree ~45 for Poisson(16))
#define ZSCALE  256.0f         // fp8 storage scale; folded out in bpr
#define BPR_BLOCKS (BATCH / 4)             // 1024, one wave per element
#define FILL_GRPS  320                     // blocks per bucket
#define FILL_BLOCKS (8 * FILL_GRPS)        // 2560
#define INIT_BLOCKS (NNODES * 16 / 256)    // 3750 (16 threads per row)

typedef float vf2 __attribute__((ext_vector_type(2)));

// unpack 8 fp8 (e4m3) from uint2, add into acc[0..8)
__device__ __forceinline__ void add_fp8x8(float* a, uint2 t) {
    vf2 p0 = __builtin_amdgcn_cvt_pk_f32_fp8(t.x, false);
    vf2 p1 = __builtin_amdgcn_cvt_pk_f32_fp8(t.x, true);
    vf2 p2 = __builtin_amdgcn_cvt_pk_f32_fp8(t.y, false);
    vf2 p3 = __builtin_amdgcn_cvt_pk_f32_fp8(t.y, true);
    a[0] += p0.x; a[1] += p0.y; a[2] += p1.x; a[3] += p1.y;
    a[4] += p2.x; a[5] += p2.y; a[6] += p3.x; a[7] += p3.y;
}

// pack 8 f32 -> 8 fp8 (e4m3) into uint2, clamped to the e4m3 range (+-448)
// so no stored byte can be NaN even for pathological (zero-degree) rows.
__device__ __forceinline__ uint2 pack_fp8x8(const float* vin) {
    float v[8];
    #pragma unroll
    for (int k = 0; k < 8; ++k) v[k] = fminf(fmaxf(vin[k], -448.0f), 448.0f);
    int lo = __builtin_amdgcn_cvt_pk_fp8_f32(v[0], v[1], 0,  false);
    lo     = __builtin_amdgcn_cvt_pk_fp8_f32(v[2], v[3], lo, true);
    int hi = __builtin_amdgcn_cvt_pk_fp8_f32(v[4], v[5], 0,  false);
    hi     = __builtin_amdgcn_cvt_pk_fp8_f32(v[6], v[7], hi, true);
    return make_uint2((unsigned)lo, (unsigned)hi);
}

// ---- bucketed ELL fill; fillc ends holding the degree --------------------
// Row buckets (XCD-local writes via blockIdx&7 round-robin heuristic):
// users: bucket = u / 10000 (0..3); items: bucket = 4 + (i - N_USERS) / 5000.
__global__ void fill_ell(const int* __restrict__ au, const int* __restrict__ ai,
                         int* __restrict__ fillc, int* __restrict__ colell) {
    const int bucket = blockIdx.x & 7;
    const int grp    = blockIdx.x >> 3;          // 0..FILL_GRPS-1
    for (int e = grp * 256 + threadIdx.x; e < N_EDGES; e += FILL_GRPS * 256) {
        int u  = au[e];
        int it = N_USERS + ai[e];
        if (u / 10000 == bucket) {
            int pos = atomicAdd(&fillc[u], 1);
            if (pos < STRIDE) colell[(u << 6) + pos] = it;
        }
        if (4 + (it - N_USERS) / 5000 == bucket) {
            int pos = atomicAdd(&fillc[it], 1);
            if (pos < STRIDE) colell[(it << 6) + pos] = u;
        }
    }
}

// ---- fused dinv/dinv2 + z0 init: 16 threads per row ----------------------
__global__ void dinv_and_init(const int* __restrict__ fillc,
                              float* __restrict__ dinv, float* __restrict__ dinv2,
                              const float4* __restrict__ ue, const float4* __restrict__ ie,
                              uint2* __restrict__ z0) {
    int i   = blockIdx.x * 256 + threadIdx.x;    // < NNODES*16
    int row = i >> 4;
    int sub = i & 15;
    float w = rsqrtf((float)fillc[row] + EPS_);
    if (sub == 0) { dinv[row] = w; dinv2[row] = w * w; }
    // 8 elems per thread: two float4 loads -> one uint2 (8 fp8)
    float4 e0, e1;
    if (row < N_USERS) {
        int b4 = row * 32 + sub * 2;             // 32 float4 per row
        e0 = ue[b4]; e1 = ue[b4 + 1];
    } else {
        int b4 = (row - N_USERS) * 32 + sub * 2;
        e0 = ie[b4]; e1 = ie[b4 + 1];
    }
    float ws = w * ZSCALE;
    float v[8] = { e0.x * ws, e0.y * ws, e0.z * ws, e0.w * ws,
                   e1.x * ws, e1.y * ws, e1.z * ws, e1.w * ws };
    z0[i] = pack_fp8x8(v);
}

// ---- SpMM, quarter-wave rows: 16 lanes x uint2 = 128B fp8 row ------------
// znxt[r] = fp8( dinv2[r] * sum_{c in N(r)} z[c] )   (scale preserved)
__global__ void spmm_full(const int* __restrict__ cnt, const int* __restrict__ colell,
                          const float* __restrict__ dinv2,
                          const uint2* __restrict__ z, uint2* __restrict__ znxt) {
    int tid = blockIdx.x * 256 + threadIdx.x;
    int row = tid >> 4;               // 16 rows per 256-thread block
    int sub = threadIdx.x & 15;
    if (row >= NNODES) return;
    int e = cnt[row];
    const int* rc = colell + (row << 6);
    float a0[8] = {0,0,0,0,0,0,0,0};
    float a1[8] = {0,0,0,0,0,0,0,0};
    int j = 0;
    for (; j + 3 < e; j += 4) {
        int c0 = rc[j], c1 = rc[j + 1], c2 = rc[j + 2], c3 = rc[j + 3];
        uint2 t0 = z[(c0 << 4) + sub];   // row stride = 16 uint2
        uint2 t1 = z[(c1 << 4) + sub];
        uint2 t2 = z[(c2 << 4) + sub];
        uint2 t3 = z[(c3 << 4) + sub];
        add_fp8x8(a0, t0); add_fp8x8(a1, t1);
        add_fp8x8(a0, t2); add_fp8x8(a1, t3);
    }
    for (; j < e; ++j) {
        uint2 t0 = z[(rc[j] << 4) + sub];
        add_fp8x8(a0, t0);
    }
    float w = dinv2[row];
    float v[8];
    #pragma unroll
    for (int k = 0; k < 8; ++k) v[k] = w * (a0[k] + a1[k]);
    znxt[(row << 4) + sub] = pack_fp8x8(v);
}

// ---- fused BPR loss, quarter-wave: one wave per element, u/p/n in q0/q1/q2
// zsum[node] = dinv*ZSCALE*emb (f32, exact) + z1 + z2 + inline layer-3 from z2.
// diff = (sp/(du*dp) - sn/(du*dn)) / (16 * ZSCALE^2)
__global__ void bpr_loss(const float4* __restrict__ ue, const float4* __restrict__ ie,
                         const uint2* __restrict__ z1, const uint2* __restrict__ z2,
                         const float* __restrict__ dinv, const float* __restrict__ dinv2,
                         const int* __restrict__ cnt, const int* __restrict__ colell,
                         const int* __restrict__ user, const int* __restrict__ pos,
                         const int* __restrict__ neg,
                         float* __restrict__ lacc, int* __restrict__ done,
                         float* __restrict__ out) {
    __shared__ float s[4];
    int gw   = (blockIdx.x * 256 + threadIdx.x) >> 6;   // batch element
    int lane = threadIdx.x & 63;
    int sub  = lane & 15;
    int q    = lane >> 4;
    int u = user[gw];
    int p = N_USERS + pos[gw] - 1;   // 1-indexed items
    int n = N_USERS + neg[gw] - 1;
    int node = (q == 1) ? p : (q == 2) ? n : u;
    float vals[8] = {0,0,0,0,0,0,0,0};
    if (q < 3) {
        // layer-0 contribution exact from the f32 embeddings
        float4 e0, e1;
        if (node < N_USERS) {
            int b4 = node * 32 + sub * 2;
            e0 = ue[b4]; e1 = ue[b4 + 1];
        } else {
            int b4 = (node - N_USERS) * 32 + sub * 2;
            e0 = ie[b4]; e1 = ie[b4 + 1];
        }
        float w0 = dinv[node] * ZSCALE;
        vals[0] = w0 * e0.x; vals[1] = w0 * e0.y;
        vals[2] = w0 * e0.z; vals[3] = w0 * e0.w;
        vals[4] = w0 * e1.x; vals[5] = w0 * e1.y;
        vals[6] = w0 * e1.z; vals[7] = w0 * e1.w;
        int o = (node << 4) + sub;
        add_fp8x8(vals, z1[o]);
        add_fp8x8(vals, z2[o]);
        // inline layer-3 gather (f32, no extra rounding)
        int e = cnt[node];
        const int* rc = colell + (node << 6);
        float a0[8] = {0,0,0,0,0,0,0,0};
        float a1[8] = {0,0,0,0,0,0,0,0};
        int j = 0;
        for (; j + 3 < e; j += 4) {
            int c0 = rc[j], c1 = rc[j + 1], c2 = rc[j + 2], c3 = rc[j + 3];
            uint2 t0 = z2[(c0 << 4) + sub];
            uint2 t1 = z2[(c1 << 4) + sub];
            uint2 t2 = z2[(c2 << 4) + sub];
            uint2 t3 = z2[(c3 << 4) + sub];
            add_fp8x8(a0, t0); add_fp8x8(a1, t1);
            add_fp8x8(a0, t2); add_fp8x8(a1, t3);
        }
        for (; j < e; ++j) {
            uint2 t0 = z2[(rc[j] << 4) + sub];
            add_fp8x8(a0, t0);
        }
        float w = dinv2[node];
        #pragma unroll
        for (int k = 0; k < 8; ++k) vals[k] += w * (a0[k] + a1[k]);
    }
    // pull quarter-0 (u-row) values into every quarter: srcLane = sub
    float dotp = 0.0f;
    #pragma unroll
    for (int k = 0; k < 8; ++k) {
        float av = __shfl(vals[k], sub);
        dotp += av * vals[k];
    }
    #pragma unroll
    for (int off = 8; off; off >>= 1) dotp += __shfl_down(dotp, off, 16);
    float sp = __shfl(dotp, 16);   // quarter 1 sub 0 holds u.p
    float sn = __shfl(dotp, 32);   // quarter 2 sub 0 holds u.n
    if (lane == 0) {
        float du = dinv[u], dp = dinv[p], dn = dinv[n];
        const float inv = 1.0f / (16.0f * ZSCALE * ZSCALE);
        float diff = (sp / (du * dp) - sn / (du * dn)) * inv;
        // log_sigmoid(x) = min(x,0) - log1p(exp(-|x|))
        s[threadIdx.x >> 6] = fminf(diff, 0.0f) - log1pf(expf(-fabsf(diff)));
    }
    __syncthreads();
    if (threadIdx.x == 0) {
        atomicAdd(lacc, s[0] + s[1] + s[2] + s[3]);
        __threadfence();
        int prev = atomicAdd(done, 1);
        if (prev == BPR_BLOCKS - 1) {
            float total = atomicAdd(lacc, 0.0f);   // coherent read
            out[0] = -total * (1.0f / (float)BATCH);
        }
    }
}

extern "C" void kernel_launch(void* const* d_in, const int* in_sizes, int n_in,
                              void* d_out, int out_size, void* d_ws, size_t ws_size,
                              hipStream_t stream) {
    const float* ue  = (const float*)d_in[0];
    const float* ie  = (const float*)d_in[1];
    const int*   au  = (const int*)d_in[2];
    const int*   ai  = (const int*)d_in[3];
    const int*   usr = (const int*)d_in[4];
    const int*   pos = (const int*)d_in[5];
    const int*   neg = (const int*)d_in[6];
    float*       out = (float*)d_out;

    const size_t ZNQ = (size_t)NNODES * 16;   // uint2 per fp8 z buffer (128 B/row)

    // ws layout (16B-aligned chunks):
    // z0 | z1 | z2 (fp8) | dinv | dinv2 | [fillc | lacc | done | pad] | colell
    uint2* z0     = (uint2*)d_ws;
    uint2* z1     = z0 + ZNQ;
    uint2* z2     = z1 + ZNQ;
    float* dinv   = (float*)(z2 + ZNQ);
    float* dinv2  = dinv + NNODES;
    int*   fillc  = (int*)(dinv2 + NNODES);
    float* lacc   = (float*)(fillc + NNODES);
    int*   done   = (int*)(lacc + 1);
    int*   colell = (int*)(lacc + 4);         // NNODES * STRIDE ints

    // fillc + lacc + done zeroed in one shot
    hipMemsetAsync(fillc, 0, (NNODES + 4) * sizeof(int), stream);

    fill_ell<<<FILL_BLOCKS, 256, 0, stream>>>(au, ai, fillc, colell);
    dinv_and_init<<<INIT_BLOCKS, 256, 0, stream>>>(fillc, dinv, dinv2,
                                                   (const float4*)ue,
                                                   (const float4*)ie, z0);

    const int FULL_BLOCKS = (NNODES + 15) / 16;   // 16 rows per block
    spmm_full<<<FULL_BLOCKS, 256, 0, stream>>>(fillc, colell, dinv2, z0, z1);
    spmm_full<<<FULL_BLOCKS, 256, 0, stream>>>(fillc, colell, dinv2, z1, z2);

    bpr_loss<<<BPR_BLOCKS, 256, 0, stream>>>((const float4*)ue, (const float4*)ie,
                                             z1, z2, dinv, dinv2, fillc, colell,
                                             usr, pos, neg, lacc, done, out);
}

// Round 12
// 171.948 us; speedup vs baseline: 6.9567x; 1.0812x over previous
//
#include <hip/hip_runtime.h>
#include <math.h>

#define N_USERS 40000
#define N_ITEMS 20000
#define NNODES  60000          // N_USERS + N_ITEMS
#define D       128
#define N_EDGES 320000
#define EPS_    1e-7f
#define BATCH   4096
#define STRIDE  64             // ELL row capacity (max degree ~45 for Poisson(16))
#define ZSCALE  256.0f         // fp8 storage scale; folded out in bpr
#define BPR_BLOCKS (BATCH / 8)             // 512: 4 waves x 2 elements each
#define FILL_GRPS  320                     // blocks per bucket
#define FILL_BLOCKS (8 * FILL_GRPS)        // 2560
#define INIT_BLOCKS (NNODES * 16 / 256)    // 3750 (16 threads per row)
#define FULL_BLOCKS (NNODES * 8 / 256)     // 1875 (8 threads per row)

typedef float vf2 __attribute__((ext_vector_type(2)));

// unpack 16 fp8 (e4m3) from uint4, add into acc[0..16)
__device__ __forceinline__ void add_fp8x16(float* a, uint4 t) {
    vf2 p0 = __builtin_amdgcn_cvt_pk_f32_fp8(t.x, false);
    vf2 p1 = __builtin_amdgcn_cvt_pk_f32_fp8(t.x, true);
    vf2 p2 = __builtin_amdgcn_cvt_pk_f32_fp8(t.y, false);
    vf2 p3 = __builtin_amdgcn_cvt_pk_f32_fp8(t.y, true);
    vf2 p4 = __builtin_amdgcn_cvt_pk_f32_fp8(t.z, false);
    vf2 p5 = __builtin_amdgcn_cvt_pk_f32_fp8(t.z, true);
    vf2 p6 = __builtin_amdgcn_cvt_pk_f32_fp8(t.w, false);
    vf2 p7 = __builtin_amdgcn_cvt_pk_f32_fp8(t.w, true);
    a[0]  += p0.x; a[1]  += p0.y; a[2]  += p1.x; a[3]  += p1.y;
    a[4]  += p2.x; a[5]  += p2.y; a[6]  += p3.x; a[7]  += p3.y;
    a[8]  += p4.x; a[9]  += p4.y; a[10] += p5.x; a[11] += p5.y;
    a[12] += p6.x; a[13] += p6.y; a[14] += p7.x; a[15] += p7.y;
}

// pack 16 f32 -> 16 fp8 (e4m3) into uint4, clamped to e4m3 range (+-448)
__device__ __forceinline__ uint4 pack_fp8x16(const float* vin) {
    float v[16];
    #pragma unroll
    for (int k = 0; k < 16; ++k) v[k] = fminf(fmaxf(vin[k], -448.0f), 448.0f);
    int w0 = __builtin_amdgcn_cvt_pk_fp8_f32(v[0],  v[1],  0,  false);
    w0     = __builtin_amdgcn_cvt_pk_fp8_f32(v[2],  v[3],  w0, true);
    int w1 = __builtin_amdgcn_cvt_pk_fp8_f32(v[4],  v[5],  0,  false);
    w1     = __builtin_amdgcn_cvt_pk_fp8_f32(v[6],  v[7],  w1, true);
    int w2 = __builtin_amdgcn_cvt_pk_fp8_f32(v[8],  v[9],  0,  false);
    w2     = __builtin_amdgcn_cvt_pk_fp8_f32(v[10], v[11], w2, true);
    int w3 = __builtin_amdgcn_cvt_pk_fp8_f32(v[12], v[13], 0,  false);
    w3     = __builtin_amdgcn_cvt_pk_fp8_f32(v[14], v[15], w3, true);
    uint4 o; o.x = (unsigned)w0; o.y = (unsigned)w1;
    o.z = (unsigned)w2; o.w = (unsigned)w3;
    return o;
}

// ---- bucketed ELL fill (int2-vectorized); fillc ends holding the degree --
// users: bucket = u/10000 (0..3); items: bucket = 4 + (i-N_USERS)/5000.
__global__ void fill_ell(const int2* __restrict__ au2, const int2* __restrict__ ai2,
                         int* __restrict__ fillc, int* __restrict__ colell) {
    const int bucket = blockIdx.x & 7;
    const int grp    = blockIdx.x >> 3;          // 0..FILL_GRPS-1
    const int NE2    = N_EDGES / 2;
    for (int i = grp * 256 + threadIdx.x; i < NE2; i += FILL_GRPS * 256) {
        int2 us = au2[i];
        int2 is = ai2[i];
        int u0 = us.x, i0 = N_USERS + is.x;
        int u1 = us.y, i1 = N_USERS + is.y;
        if (u0 / 10000 == bucket) {
            int pos = atomicAdd(&fillc[u0], 1);
            if (pos < STRIDE) colell[(u0 << 6) + pos] = i0;
        }
        if (u1 / 10000 == bucket) {
            int pos = atomicAdd(&fillc[u1], 1);
            if (pos < STRIDE) colell[(u1 << 6) + pos] = i1;
        }
        if (4 + (i0 - N_USERS) / 5000 == bucket) {
            int pos = atomicAdd(&fillc[i0], 1);
            if (pos < STRIDE) colell[(i0 << 6) + pos] = u0;
        }
        if (4 + (i1 - N_USERS) / 5000 == bucket) {
            int pos = atomicAdd(&fillc[i1], 1);
            if (pos < STRIDE) colell[(i1 << 6) + pos] = u1;
        }
    }
}

// ---- z0 init: 16 threads per row, w computed from degree -----------------
__global__ void init_z(const int* __restrict__ fillc,
                       const float4* __restrict__ ue, const float4* __restrict__ ie,
                       uint2* __restrict__ z0) {
    int i   = blockIdx.x * 256 + threadIdx.x;    // < NNODES*16
    int row = i >> 4;
    int sub = i & 15;
    float w = rsqrtf((float)fillc[row] + EPS_) * ZSCALE;
    float4 e0, e1;
    if (row < N_USERS) {
        int b4 = row * 32 + sub * 2;             // 32 float4 per row
        e0 = ue[b4]; e1 = ue[b4 + 1];
    } else {
        int b4 = (row - N_USERS) * 32 + sub * 2;
        e0 = ie[b4]; e1 = ie[b4 + 1];
    }
    float v[8] = { e0.x * w, e0.y * w, e0.z * w, e0.w * w,
                   e1.x * w, e1.y * w, e1.z * w, e1.w * w };
    float c[8];
    #pragma unroll
    for (int k = 0; k < 8; ++k) c[k] = fminf(fmaxf(v[k], -448.0f), 448.0f);
    int lo = __builtin_amdgcn_cvt_pk_fp8_f32(c[0], c[1], 0,  false);
    lo     = __builtin_amdgcn_cvt_pk_fp8_f32(c[2], c[3], lo, true);
    int hi = __builtin_amdgcn_cvt_pk_fp8_f32(c[4], c[5], 0,  false);
    hi     = __builtin_amdgcn_cvt_pk_fp8_f32(c[6], c[7], hi, true);
    z0[i] = make_uint2((unsigned)lo, (unsigned)hi);
}

// ---- SpMM, 8-lane subgroup rows: 8 lanes x uint4 = 128B fp8 row ----------
// znxt[r] = fp8( (1/(deg+eps)) * sum_{c in N(r)} z[c] )   (scale preserved)
__global__ void spmm_full(const int* __restrict__ cnt, const int* __restrict__ colell,
                          const uint4* __restrict__ z, uint4* __restrict__ znxt) {
    int tid = blockIdx.x * 256 + threadIdx.x;
    int row = tid >> 3;               // 32 rows per 256-thread block
    int sub = threadIdx.x & 7;
    int e = cnt[row];
    const int* rc = colell + (row << 6);
    float a0[16], a1[16];
    #pragma unroll
    for (int k = 0; k < 16; ++k) { a0[k] = 0.f; a1[k] = 0.f; }
    int j = 0;
    for (; j + 3 < e; j += 4) {
        int c0 = rc[j], c1 = rc[j + 1], c2 = rc[j + 2], c3 = rc[j + 3];
        uint4 t0 = z[(c0 << 3) + sub];   // row stride = 8 uint4
        uint4 t1 = z[(c1 << 3) + sub];
        uint4 t2 = z[(c2 << 3) + sub];
        uint4 t3 = z[(c3 << 3) + sub];
        add_fp8x16(a0, t0); add_fp8x16(a1, t1);
        add_fp8x16(a0, t2); add_fp8x16(a1, t3);
    }
    for (; j < e; ++j) {
        uint4 t0 = z[(rc[j] << 3) + sub];
        add_fp8x16(a0, t0);
    }
    float w = 1.0f / ((float)e + EPS_);   // dinv^2
    float v[16];
    #pragma unroll
    for (int k = 0; k < 16; ++k) v[k] = w * (a0[k] + a1[k]);
    znxt[(row << 3) + sub] = pack_fp8x16(v);
}

// ---- fused BPR loss: 2 elements per wave; u/p/n rows in 8-lane subgroups
// sg 0-2 = elem A's u/p/n, sg 4-6 = elem B's; sg 3/7 idle.
// zsum = dinv*ZSCALE*emb (f32 exact) + z1 + z2 + inline layer-3 from z2.
// diff = (sp/(du*dp) - sn/(du*dn)) / (16 * ZSCALE^2)
__global__ void bpr_loss(const float4* __restrict__ ue, const float4* __restrict__ ie,
                         const uint4* __restrict__ z1, const uint4* __restrict__ z2,
                         const int* __restrict__ cnt, const int* __restrict__ colell,
                         const int* __restrict__ user, const int* __restrict__ pos,
                         const int* __restrict__ neg,
                         float* __restrict__ lacc, int* __restrict__ done,
                         float* __restrict__ out) {
    __shared__ float s[8];
    int wave = (blockIdx.x * 256 + threadIdx.x) >> 6;   // global wave id
    int lane = threadIdx.x & 63;
    int sg   = lane >> 3;          // 0..7
    int sub  = lane & 7;
    int half = sg >> 2;            // 0 = elem A, 1 = elem B
    int sgl  = sg & 3;             // 0=u 1=p 2=n 3=idle
    int el   = wave * 2 + half;
    int u = user[el];
    int p = N_USERS + pos[el] - 1;  // 1-indexed items
    int n = N_USERS + neg[el] - 1;
    int node = (sgl == 1) ? p : (sgl == 2) ? n : u;
    float cnode = 0.0f;
    float vals[16];
    #pragma unroll
    for (int k = 0; k < 16; ++k) vals[k] = 0.0f;
    if (sgl < 3) {
        int e = cnt[node];
        cnode = (float)e;
        // layer-0 exact from f32 embeddings: 4 float4 per lane
        const float4* eb = (node < N_USERS) ? ue : ie;
        int b4 = ((node < N_USERS) ? node : node - N_USERS) * 32 + sub * 4;
        float4 e0 = eb[b4], e1 = eb[b4 + 1], e2 = eb[b4 + 2], e3 = eb[b4 + 3];
        float w0 = rsqrtf(cnode + EPS_) * ZSCALE;
        vals[0]  = w0 * e0.x; vals[1]  = w0 * e0.y; vals[2]  = w0 * e0.z; vals[3]  = w0 * e0.w;
        vals[4]  = w0 * e1.x; vals[5]  = w0 * e1.y; vals[6]  = w0 * e1.z; vals[7]  = w0 * e1.w;
        vals[8]  = w0 * e2.x; vals[9]  = w0 * e2.y; vals[10] = w0 * e2.z; vals[11] = w0 * e2.w;
        vals[12] = w0 * e3.x; vals[13] = w0 * e3.y; vals[14] = w0 * e3.z; vals[15] = w0 * e3.w;
        int o = (node << 3) + sub;
        add_fp8x16(vals, z1[o]);
        add_fp8x16(vals, z2[o]);
        // inline layer-3 gather from z2 (f32, no extra rounding)
        const int* rc = colell + (node << 6);
        float a0[16], a1[16];
        #pragma unroll
        for (int k = 0; k < 16; ++k) { a0[k] = 0.f; a1[k] = 0.f; }
        int j = 0;
        for (; j + 3 < e; j += 4) {
            int c0 = rc[j], c1 = rc[j + 1], c2 = rc[j + 2], c3 = rc[j + 3];
            uint4 t0 = z2[(c0 << 3) + sub];
            uint4 t1 = z2[(c1 << 3) + sub];
            uint4 t2 = z2[(c2 << 3) + sub];
            uint4 t3 = z2[(c3 << 3) + sub];
            add_fp8x16(a0, t0); add_fp8x16(a1, t1);
            add_fp8x16(a0, t2); add_fp8x16(a1, t3);
        }
        for (; j < e; ++j) {
            uint4 t0 = z2[(rc[j] << 3) + sub];
            add_fp8x16(a0, t0);
        }
        float w2 = 1.0f / (cnode + EPS_);   // dinv^2
        #pragma unroll
        for (int k = 0; k < 16; ++k) vals[k] += w2 * (a0[k] + a1[k]);
    }
    // pull the u-subgroup (sg0 / sg4) values into all subgroups of the half
    int usrc = sub | (lane & 32);
    float dotp = 0.0f;
    #pragma unroll
    for (int k = 0; k < 16; ++k) dotp += __shfl(vals[k], usrc) * vals[k];
    dotp += __shfl_down(dotp, 4, 8);
    dotp += __shfl_down(dotp, 2, 8);
    dotp += __shfl_down(dotp, 1, 8);
    // subgroup heads now hold: lane (lane&32)+8 -> u.p, +16 -> u.n
    float sp = __shfl(dotp, (lane & 32) + 8);
    float sn = __shfl(dotp, (lane & 32) + 16);
    float cu = __shfl(cnode, (lane & 32) + 0);
    float cp = __shfl(cnode, (lane & 32) + 8);
    float cn = __shfl(cnode, (lane & 32) + 16);
    if ((lane & 31) == 0) {   // lane 0 (elem A) and lane 32 (elem B)
        float du = rsqrtf(cu + EPS_), dp = rsqrtf(cp + EPS_), dn = rsqrtf(cn + EPS_);
        const float inv = 1.0f / (16.0f * ZSCALE * ZSCALE);
        float diff = (sp / (du * dp) - sn / (du * dn)) * inv;
        // log_sigmoid(x) = min(x,0) - log1p(exp(-|x|))
        s[(threadIdx.x >> 6) * 2 + half] =
            fminf(diff, 0.0f) - log1pf(expf(-fabsf(diff)));
    }
    __syncthreads();
    if (threadIdx.x == 0) {
        float t = s[0] + s[1] + s[2] + s[3] + s[4] + s[5] + s[6] + s[7];
        atomicAdd(lacc, t);
        __threadfence();
        int prev = atomicAdd(done, 1);
        if (prev == BPR_BLOCKS - 1) {
            float total = atomicAdd(lacc, 0.0f);   // coherent read
            out[0] = -total * (1.0f / (float)BATCH);
        }
    }
}

extern "C" void kernel_launch(void* const* d_in, const int* in_sizes, int n_in,
                              void* d_out, int out_size, void* d_ws, size_t ws_size,
                              hipStream_t stream) {
    const float* ue  = (const float*)d_in[0];
    const float* ie  = (const float*)d_in[1];
    const int*   au  = (const int*)d_in[2];
    const int*   ai  = (const int*)d_in[3];
    const int*   usr = (const int*)d_in[4];
    const int*   pos = (const int*)d_in[5];
    const int*   neg = (const int*)d_in[6];
    float*       out = (float*)d_out;

    const size_t ZQ4 = (size_t)NNODES * 8;    // uint4 per fp8 z buffer (128 B/row)

    // ws layout (16B-aligned chunks):
    // z0 | z1 | z2 (fp8) | [fillc | lacc | done | pad] | colell
    uint4* z0     = (uint4*)d_ws;
    uint4* z1     = z0 + ZQ4;
    uint4* z2     = z1 + ZQ4;
    int*   fillc  = (int*)(z2 + ZQ4);
    float* lacc   = (float*)(fillc + NNODES);
    int*   done   = (int*)(lacc + 1);
    int*   colell = (int*)(lacc + 4);         // NNODES * STRIDE ints

    // fillc + lacc + done zeroed in one shot
    hipMemsetAsync(fillc, 0, (NNODES + 4) * sizeof(int), stream);

    fill_ell<<<FILL_BLOCKS, 256, 0, stream>>>((const int2*)au, (const int2*)ai,
                                              fillc, colell);
    init_z<<<INIT_BLOCKS, 256, 0, stream>>>(fillc, (const float4*)ue,
                                            (const float4*)ie, (uint2*)z0);

    spmm_full<<<FULL_BLOCKS, 256, 0, stream>>>(fillc, colell, z0, z1);
    spmm_full<<<FULL_BLOCKS, 256, 0, stream>>>(fillc, colell, z1, z2);

    bpr_loss<<<BPR_BLOCKS, 256, 0, stream>>>((const float4*)ue, (const float4*)ie,
                                             z1, z2, fillc, colell,
                                             usr, pos, neg, lacc, done, out);
}